// Round 1
// baseline (69.895 us; speedup 1.0000x reference)
//
#include <hip/hip_runtime.h>

// Ordered product of 4,194,304 (+1 repeat) 2x2 float32 matrices; out = e0^T * M.
//
// Two-kernel tree reduction (fusion with agent-scope sync measured +20us three
// times in a prior session -> do not revisit).
//
// This version vs the 67us baseline:
//  1) Transition table staged as TWO float2 LDS arrays (row0 / row1) instead of
//     one float4 array. float4 entries start at bank 4i%32 -> only 8 start-bank
//     classes -> ~6.5-way conflicts on random gathers (~2.3x). float2 entries
//     start at bank 2i%32 -> 16 classes -> ~3.3-way (~1.2x, near free).
//     Two ds_read_b64 replace one conflicted ds_read_b128.
//  2) Wave reduce flipped to accumulate at the HIGH lane: rounds 1-8 use DPP
//     row_shl, rounds 16/32 use DPP row_bcast15/row_bcast31 -> zero ds_swizzle,
//     keeping the LDS pipe free for the gathers. Representative = lane 63.
//  3) 256 blocks x 512 threads x 32 tokens/thread (was 512x512x16): phase 2
//     shrinks to 256 partials / 4 waves; still exactly 1 block/CU resident.
//     Per-thread work split into two independent 16-token chains (ILP).
// mm() stays on <2 x float> rows so the backend emits v_pk_fma_f32.

#define T_TOKENS 4194304
#define TPB      512
#define TOKS     32                                  // tokens per thread
#define BLOCKS   (T_TOKENS / (TPB * TOKS))           // 256
#define TPB2     256                                 // phase-2 threads == BLOCKS

typedef float v2f __attribute__((ext_vector_type(2)));

struct m22 { v2f r0, r1; };

__device__ __forceinline__ m22 mm(const m22 A, const m22 B) {
    m22 C;
    C.r0 = A.r0.x * B.r0 + A.r0.y * B.r1;   // -> v_pk_fma_f32 candidates
    C.r1 = A.r1.x * B.r0 + A.r1.y * B.r1;
    return C;
}

__device__ __forceinline__ float4 to4(const m22 m) {
    return make_float4(m.r0.x, m.r0.y, m.r1.x, m.r1.y);
}
__device__ __forceinline__ m22 fr4(const float4 f) {
    return m22{ (v2f){f.x, f.y}, (v2f){f.z, f.w} };
}

// Generic 4-dword DPP move. Lanes with an invalid source (or masked-off rows)
// keep their own value; the reduce tree never consumes those lanes.
template <int CTRL, int ROWM>
__device__ __forceinline__ m22 dpp4(const m22 m) {
    m22 o;
    o.r0.x = __int_as_float(__builtin_amdgcn_update_dpp(
        __float_as_int(m.r0.x), __float_as_int(m.r0.x), CTRL, ROWM, 0xF, false));
    o.r0.y = __int_as_float(__builtin_amdgcn_update_dpp(
        __float_as_int(m.r0.y), __float_as_int(m.r0.y), CTRL, ROWM, 0xF, false));
    o.r1.x = __int_as_float(__builtin_amdgcn_update_dpp(
        __float_as_int(m.r1.x), __float_as_int(m.r1.x), CTRL, ROWM, 0xF, false));
    o.r1.y = __int_as_float(__builtin_amdgcn_update_dpp(
        __float_as_int(m.r1.y), __float_as_int(m.r1.y), CTRL, ROWM, 0xF, false));
    return o;
}

// Ordered wave reduce accumulating at the HIGH lane (left operand = lower lane
// = earlier tokens). After round s, lane j (j%2s == 2s-1) holds the product of
// segment [j-2s+1, j]. Lane 63 ends with the full 64-lane ordered product.
// Rounds 16/32 use row_bcast15/31 (pure VALU DPP, no LDS pipe).
__device__ __forceinline__ m22 wave_reduce_hi(m22 m) {
    m = mm(dpp4<0x101, 0xF>(m), m);   // row_shl:1
    m = mm(dpp4<0x102, 0xF>(m), m);   // row_shl:2
    m = mm(dpp4<0x104, 0xF>(m), m);   // row_shl:4
    m = mm(dpp4<0x108, 0xF>(m), m);   // row_shl:8
    m = mm(dpp4<0x142, 0xA>(m), m);   // row_bcast15 -> rows 1,3 (lanes 16-31 <- 15, 48-63 <- 47)
    m = mm(dpp4<0x143, 0xC>(m), m);   // row_bcast31 -> rows 2,3 (lanes 32-63 <- 31)
    return m;
}

// Phase 1: 256 blocks x 512 threads (8 waves), 32 tokens/thread.
__global__ __launch_bounds__(TPB) void scan_phase1(const int4* __restrict__ tok4,
                                                   const float4* __restrict__ ls,
                                                   float4* __restrict__ partials) {
    __shared__ v2f s_r0[128];             // row 0 of each 2x2, 8B stride
    __shared__ v2f s_r1[128];             // row 1
    __shared__ float4 sm[8];

    const int tid = threadIdx.x;
    if (tid < 128) {
        const float4 e = ls[tid];
        s_r0[tid] = (v2f){e.x, e.y};
        s_r1[tid] = (v2f){e.z, e.w};
    }
    __syncthreads();

#define LDM(i) (m22{ s_r0[(i)], s_r1[(i)] })

    const int4* p = tok4 + (size_t)(blockIdx.x * TPB + tid) * (TOKS / 4);
    const int4 t0 = p[0];
    const int4 t1 = p[1];
    const int4 t2 = p[2];
    const int4 t3 = p[3];
    const int4 t4 = p[4];
    const int4 t5 = p[5];
    const int4 t6 = p[6];
    const int4 t7 = p[7];

    // Two independent 16-token chains (ILP), merged with one mm.
    m22 a = LDM(t0.x);
    a = mm(a, LDM(t0.y)); a = mm(a, LDM(t0.z)); a = mm(a, LDM(t0.w));
    a = mm(a, LDM(t1.x)); a = mm(a, LDM(t1.y)); a = mm(a, LDM(t1.z)); a = mm(a, LDM(t1.w));
    a = mm(a, LDM(t2.x)); a = mm(a, LDM(t2.y)); a = mm(a, LDM(t2.z)); a = mm(a, LDM(t2.w));
    a = mm(a, LDM(t3.x)); a = mm(a, LDM(t3.y)); a = mm(a, LDM(t3.z)); a = mm(a, LDM(t3.w));

    m22 b = LDM(t4.x);
    b = mm(b, LDM(t4.y)); b = mm(b, LDM(t4.z)); b = mm(b, LDM(t4.w));
    b = mm(b, LDM(t5.x)); b = mm(b, LDM(t5.y)); b = mm(b, LDM(t5.z)); b = mm(b, LDM(t5.w));
    b = mm(b, LDM(t6.x)); b = mm(b, LDM(t6.y)); b = mm(b, LDM(t6.z)); b = mm(b, LDM(t6.w));
    b = mm(b, LDM(t7.x)); b = mm(b, LDM(t7.y)); b = mm(b, LDM(t7.z)); b = mm(b, LDM(t7.w));

    m22 m = mm(a, b);

    m = wave_reduce_hi(m);                // lane 63 of each wave: wave product

    if ((tid & 63) == 63) sm[tid >> 6] = to4(m);
    __syncthreads();
    if (tid == 0) {
        const m22 q01 = mm(fr4(sm[0]), fr4(sm[1]));
        const m22 q23 = mm(fr4(sm[2]), fr4(sm[3]));
        const m22 q45 = mm(fr4(sm[4]), fr4(sm[5]));
        const m22 q67 = mm(fr4(sm[6]), fr4(sm[7]));
        partials[blockIdx.x] = to4(mm(mm(q01, q23), mm(q45, q67)));
    }
#undef LDM
}

// Phase 2: one 256-thread block (4 waves), one partial per thread, ordered
// reduce, apply the doubled last-token matrix, write row 0 (v0 = [1,0]).
__global__ __launch_bounds__(TPB2) void scan_phase2(const float4* __restrict__ partials,
                                                    const int* __restrict__ tokens,
                                                    const float4* __restrict__ ls,
                                                    float* __restrict__ out) {
    const int tid = threadIdx.x;
    m22 m = fr4(partials[tid]);           // coalesced 4 KB

    m = wave_reduce_hi(m);

    __shared__ float4 sf[4];
    if ((tid & 63) == 63) sf[tid >> 6] = to4(m);
    __syncthreads();
    if (tid == 0) {
        const m22 q01 = mm(fr4(sf[0]), fr4(sf[1]));
        const m22 q23 = mm(fr4(sf[2]), fr4(sf[3]));
        m22 M = mm(q01, q23);
        M = mm(M, fr4(ls[tokens[T_TOKENS - 1]]));   // last token applied twice
        out[0] = M.r0.x;
        out[1] = M.r0.y;
    }
}

extern "C" void kernel_launch(void* const* d_in, const int* in_sizes, int n_in,
                              void* d_out, int out_size, void* d_ws, size_t ws_size,
                              hipStream_t stream) {
    const int*    tokens = (const int*)d_in[0];     // (T,) int32
    const float4* ls     = (const float4*)d_in[1];  // (128,2,2) f32 == 128 x float4
    float*  out      = (float*)d_out;               // 2 floats
    float4* partials = (float4*)d_ws;               // 256 * 16 B = 4 KB scratch

    scan_phase1<<<BLOCKS, TPB, 0, stream>>>((const int4*)tokens, ls, partials);
    scan_phase2<<<1, TPB2, 0, stream>>>(partials, tokens, ls, out);
}

// Round 2
// 68.272 us; speedup vs baseline: 1.0238x; 1.0238x over previous
//
#include <hip/hip_runtime.h>

// Ordered product of 4,194,304 (+1 repeat) 2x2 float32 matrices; out = e0^T * M.
//
// Two-kernel tree reduction (fusion with agent-scope sync measured +20us three
// times in a prior session -> do not revisit).
//
// Config history:
//  - R0 (66.95us): 512 blocks x 512 thr x 16 tok, float4 LDS table, swizzle
//    reduce. 2 blocks/CU = 4 waves/SIMD.
//  - R1 (69.89us): 256 blocks x 512 thr x 32 tok, v2f table, DPP reduce.
//    REGRESSED: 1 block/CU = 2 waves/SIMD cannot hide the dependent
//    ds_read-gather -> fma chain latency. Occupancy was the lever, not LDS.
//  - R2 (this): R0's grid (512x512x16, 4 waves/SIMD) + R1's LDS improvements:
//      * table as TWO v2f arrays (8B stride -> 16 start-bank classes vs 8 for
//        float4 -> ~3.3-way conflicts instead of ~6.5-way on random gathers)
//      * wave reduce entirely in DPP (row_shl + row_bcast15/31), zero LDS ops.
// mm() stays on <2 x float> rows so the backend emits v_pk_fma_f32.

#define T_TOKENS 4194304
#define TPB      512
#define TOKS     16                                  // tokens per thread
#define BLOCKS   (T_TOKENS / (TPB * TOKS))           // 512 -> 2 blocks/CU

typedef float v2f __attribute__((ext_vector_type(2)));

struct m22 { v2f r0, r1; };

__device__ __forceinline__ m22 mm(const m22 A, const m22 B) {
    m22 C;
    C.r0 = A.r0.x * B.r0 + A.r0.y * B.r1;   // -> v_pk_fma_f32 candidates
    C.r1 = A.r1.x * B.r0 + A.r1.y * B.r1;
    return C;
}

__device__ __forceinline__ float4 to4(const m22 m) {
    return make_float4(m.r0.x, m.r0.y, m.r1.x, m.r1.y);
}
__device__ __forceinline__ m22 fr4(const float4 f) {
    return m22{ (v2f){f.x, f.y}, (v2f){f.z, f.w} };
}

// Generic 4-dword DPP move. Lanes with an invalid source (or masked-off rows)
// keep their own value; the reduce tree never consumes those lanes.
template <int CTRL, int ROWM>
__device__ __forceinline__ m22 dpp4(const m22 m) {
    m22 o;
    o.r0.x = __int_as_float(__builtin_amdgcn_update_dpp(
        __float_as_int(m.r0.x), __float_as_int(m.r0.x), CTRL, ROWM, 0xF, false));
    o.r0.y = __int_as_float(__builtin_amdgcn_update_dpp(
        __float_as_int(m.r0.y), __float_as_int(m.r0.y), CTRL, ROWM, 0xF, false));
    o.r1.x = __int_as_float(__builtin_amdgcn_update_dpp(
        __float_as_int(m.r1.x), __float_as_int(m.r1.x), CTRL, ROWM, 0xF, false));
    o.r1.y = __int_as_float(__builtin_amdgcn_update_dpp(
        __float_as_int(m.r1.y), __float_as_int(m.r1.y), CTRL, ROWM, 0xF, false));
    return o;
}

// Ordered wave reduce accumulating at the HIGH lane (left operand = lower lane
// = earlier tokens). After round s, lane j (j%2s == 2s-1) holds the product of
// segment [j-2s+1, j]. Lane 63 ends with the full 64-lane ordered product.
// Rounds 16/32 use row_bcast15/31 (pure VALU DPP, no LDS pipe).
__device__ __forceinline__ m22 wave_reduce_hi(m22 m) {
    m = mm(dpp4<0x101, 0xF>(m), m);   // row_shl:1
    m = mm(dpp4<0x102, 0xF>(m), m);   // row_shl:2
    m = mm(dpp4<0x104, 0xF>(m), m);   // row_shl:4
    m = mm(dpp4<0x108, 0xF>(m), m);   // row_shl:8
    m = mm(dpp4<0x142, 0xA>(m), m);   // row_bcast15 -> rows 1,3 (16-31 <- 15, 48-63 <- 47)
    m = mm(dpp4<0x143, 0xC>(m), m);   // row_bcast31 -> rows 2,3 (32-63 <- 31)
    return m;
}

// Phase 1: 512 blocks x 512 threads (8 waves), 16 tokens/thread.
__global__ __launch_bounds__(TPB) void scan_phase1(const int4* __restrict__ tok4,
                                                   const float4* __restrict__ ls,
                                                   float4* __restrict__ partials) {
    __shared__ v2f s_r0[128];             // row 0 of each 2x2, 8B stride
    __shared__ v2f s_r1[128];             // row 1
    __shared__ float4 sm[8];

    const int tid = threadIdx.x;
    if (tid < 128) {
        const float4 e = ls[tid];
        s_r0[tid] = (v2f){e.x, e.y};
        s_r1[tid] = (v2f){e.z, e.w};
    }
    __syncthreads();

#define LDM(i) (m22{ s_r0[(i)], s_r1[(i)] })

    const int4* p = tok4 + (size_t)(blockIdx.x * TPB + tid) * (TOKS / 4);
    const int4 t0 = p[0];
    const int4 t1 = p[1];
    const int4 t2 = p[2];
    const int4 t3 = p[3];

    m22 m = LDM(t0.x);
    m = mm(m, LDM(t0.y));
    m = mm(m, LDM(t0.z));
    m = mm(m, LDM(t0.w));
    m = mm(m, LDM(t1.x));
    m = mm(m, LDM(t1.y));
    m = mm(m, LDM(t1.z));
    m = mm(m, LDM(t1.w));
    m = mm(m, LDM(t2.x));
    m = mm(m, LDM(t2.y));
    m = mm(m, LDM(t2.z));
    m = mm(m, LDM(t2.w));
    m = mm(m, LDM(t3.x));
    m = mm(m, LDM(t3.y));
    m = mm(m, LDM(t3.z));
    m = mm(m, LDM(t3.w));

    m = wave_reduce_hi(m);                // lane 63 of each wave: wave product

    if ((tid & 63) == 63) sm[tid >> 6] = to4(m);
    __syncthreads();
    if (tid == 0) {
        const m22 q01 = mm(fr4(sm[0]), fr4(sm[1]));
        const m22 q23 = mm(fr4(sm[2]), fr4(sm[3]));
        const m22 q45 = mm(fr4(sm[4]), fr4(sm[5]));
        const m22 q67 = mm(fr4(sm[6]), fr4(sm[7]));
        partials[blockIdx.x] = to4(mm(mm(q01, q23), mm(q45, q67)));
    }
#undef LDM
}

// Phase 2: one 512-thread block, one partial per thread, ordered reduce,
// apply the doubled last-token matrix, write row 0 (v0 = [1,0]).
__global__ __launch_bounds__(TPB) void scan_phase2(const float4* __restrict__ partials,
                                                   const int* __restrict__ tokens,
                                                   const float4* __restrict__ ls,
                                                   float* __restrict__ out) {
    const int tid = threadIdx.x;
    m22 m = fr4(partials[tid]);           // coalesced 8 KB

    m = wave_reduce_hi(m);

    __shared__ float4 sf[8];
    if ((tid & 63) == 63) sf[tid >> 6] = to4(m);
    __syncthreads();
    if (tid == 0) {
        const m22 q01 = mm(fr4(sf[0]), fr4(sf[1]));
        const m22 q23 = mm(fr4(sf[2]), fr4(sf[3]));
        const m22 q45 = mm(fr4(sf[4]), fr4(sf[5]));
        const m22 q67 = mm(fr4(sf[6]), fr4(sf[7]));
        m22 M = mm(mm(q01, q23), mm(q45, q67));
        M = mm(M, fr4(ls[tokens[T_TOKENS - 1]]));   // last token applied twice
        out[0] = M.r0.x;
        out[1] = M.r0.y;
    }
}

extern "C" void kernel_launch(void* const* d_in, const int* in_sizes, int n_in,
                              void* d_out, int out_size, void* d_ws, size_t ws_size,
                              hipStream_t stream) {
    const int*    tokens = (const int*)d_in[0];     // (T,) int32
    const float4* ls     = (const float4*)d_in[1];  // (128,2,2) f32 == 128 x float4
    float*  out      = (float*)d_out;               // 2 floats
    float4* partials = (float4*)d_ws;               // 512 * 16 B = 8 KB scratch

    scan_phase1<<<BLOCKS, TPB, 0, stream>>>((const int4*)tokens, ls, partials);
    scan_phase2<<<1, TPB, 0, stream>>>(partials, tokens, ls, out);
}